// Round 9
// baseline (1037.005 us; speedup 1.0000x reference)
//
#include <hip/hip_runtime.h>
#include <hip/hip_bf16.h>
#include <math.h>

#define VOCAB 50000
#define EMB 100
#define HID 128
#define NPROD 10000
#define PEMB 50
#define BSZ 256
#define TLEN 512
#define INDIM 150
#define G4 512        // 4*HID
#define RPB 16        // batch rows per k_lstm block
#define NBLK (BSZ/RPB)

typedef __attribute__((ext_vector_type(4))) float f32x4;
typedef __attribute__((ext_vector_type(8))) short short8;
typedef __attribute__((ext_vector_type(4))) short short4v;

__device__ __forceinline__ float sigm(float x) {
    return __builtin_amdgcn_rcpf(1.f + __expf(-x));
}
__device__ __forceinline__ float tanh_fast(float x) {
    float e = __expf(-2.f * fabsf(x));
    float r = (1.f - e) * __builtin_amdgcn_rcpf(1.f + e);
    return __builtin_copysignf(r, x);
}
__device__ __forceinline__ short f2bf(float f) {
    __hip_bfloat16 h = __float2bfloat16(f);
    return __builtin_bit_cast(short, h);
}
__device__ __forceinline__ float bf2f(short s) {
    __hip_bfloat16 h = __builtin_bit_cast(__hip_bfloat16, s);
    return __bfloat162float(h);
}
// permuted column j (= 4*unit + gate) -> original gate row g (= gate*128 + unit)
__device__ __forceinline__ int jperm(int j) { return ((j & 3) << 7) + (j >> 2); }

// ---------------- K0: Wt[d][j] = W_ih[g(j)][d]  (transpose + gate-interleave permute) ----------------
__global__ void k_transpose(const float* __restrict__ W_ih, float* __restrict__ Wt) {
    int idx = blockIdx.x * blockDim.x + threadIdx.x;
    if (idx < INDIM * G4) {
        int d = idx / G4, j = idx % G4;
        Wt[idx] = W_ih[jperm(j) * INDIM + d];
    }
}

// ---------------- K1: pbias[b][j] = b_ih[g(j)]+b_hh[g(j)] + pemb[product[b]] . W_ih[g(j),100:] ----------------
__global__ void k_pbias(const int* __restrict__ product,
                        const float* __restrict__ pemb,
                        const float* __restrict__ Wt,
                        const float* __restrict__ b_ih,
                        const float* __restrict__ b_hh,
                        float* __restrict__ pbias) {
    __shared__ float ep_s[PEMB];
    int b = blockIdx.x;
    int tid = threadIdx.x;
    int p = product[b];
    if (tid < PEMB) ep_s[tid] = pemb[p * PEMB + tid];
    __syncthreads();
    int j0 = tid, j1 = tid + 256;
    int g0 = jperm(j0), g1 = jperm(j1);
    float a0 = b_ih[g0] + b_hh[g0];
    float a1 = b_ih[g1] + b_hh[g1];
    #pragma unroll 5
    for (int d = 0; d < PEMB; ++d) {
        float e = ep_s[d];
        a0 += e * Wt[(EMB + d) * G4 + j0];
        a1 += e * Wt[(EMB + d) * G4 + j1];
    }
    pbias[b * G4 + j0] = a0;
    pbias[b * G4 + j1] = a1;
}

// ---------------- K2: table[v][j] = emb[v][:] . W_ih[g(j)][:100]  (permutation via Wt) ----------------
__global__ void k_table(const float* __restrict__ emb,
                        const float* __restrict__ Wt,
                        float* __restrict__ table) {
    __shared__ __align__(16) float es[16 * EMB];
    int v0 = blockIdx.x * 16;
    int tid = threadIdx.x;
    for (int l = tid; l < 16 * EMB; l += 256) es[l] = emb[v0 * EMB + l];
    __syncthreads();
    float acc0[16], acc1[16];
    #pragma unroll
    for (int r = 0; r < 16; ++r) { acc0[r] = 0.f; acc1[r] = 0.f; }
    #pragma unroll 5
    for (int k4 = 0; k4 < EMB / 4; ++k4) {
        float w0[4], w1[4];
        #pragma unroll
        for (int j = 0; j < 4; ++j) {
            w0[j] = Wt[(k4 * 4 + j) * G4 + tid];
            w1[j] = Wt[(k4 * 4 + j) * G4 + tid + 256];
        }
        #pragma unroll
        for (int r = 0; r < 16; ++r) {
            float4 e = *reinterpret_cast<const float4*>(&es[r * EMB + k4 * 4]);
            acc0[r] += e.x * w0[0] + e.y * w0[1] + e.z * w0[2] + e.w * w0[3];
            acc1[r] += e.x * w1[0] + e.y * w1[1] + e.z * w1[2] + e.w * w1[3];
        }
    }
    #pragma unroll
    for (int r = 0; r < 16; ++r) {
        table[(v0 + r) * G4 + tid]       = acc0[r];
        table[(v0 + r) * G4 + tid + 256] = acc1[r];
    }
}

// ---------------- K3: MFMA LSTM, 16 batch rows / block, 8 waves, 1 barrier/step ----------------
// D[j][m] = sum_u Wperm[j][u] * h[m][u]:  A = Wperm fragments (resident, AGPR-legal),
// B = h fragments (LDS, bf16 hi/lo, XOR-swizzled).  C/D layout: col(lane&15)=batch row m,
// row((lane>>4)*4+reg)=j within tile; with j=4*unit+gate, reg IS the gate -> all 4 gates
// of one unit land in one lane's 4 acc regs. c-state per lane (f32, exact).
__global__ void
__attribute__((amdgpu_flat_work_group_size(512, 512), amdgpu_waves_per_eu(2, 2)))
k_lstm(const int* __restrict__ review,
       const float* __restrict__ W_hh,
       const float* __restrict__ table,
       const float* __restrict__ pbias,
       const float* __restrict__ fc_w,
       const float* __restrict__ fc_b,
       float* __restrict__ out) {
    __shared__ int rv_s[RPB][TLEN + 1];           // +1: stride 513 breaks bank aliasing
    __shared__ short hbuf[2][2][RPB * HID];       // [buf][hi/lo][swizzled row*128+unit]

    const int tid = threadIdx.x;
    const int w   = tid >> 6;        // wave 0..7 -> owns j-cols [64w, 64w+64)
    const int l   = tid & 63;
    const int row = l & 15;          // batch row within tile (B-frag col / D col)
    const int lk  = l >> 4;          // 0..3
    const int b0  = blockIdx.x * RPB;

    // stage review rows (coalesced)
    #pragma unroll 1
    for (int r = 0; r < RPB; ++r)
        rv_s[r][tid] = review[(b0 + r) * TLEN + tid];
    // zero h double-buffers (16 KB)
    {
        int4 z = {0, 0, 0, 0};
        int4* hz = (int4*)hbuf;
        hz[tid] = z; hz[tid + 512] = z;
    }

    // resident A fragments: W rows for this lane, bf16 hi/lo split.
    // A[jrow][k]: lane holds jrow = l&15 (within tile), k = (l>>4)*8 + 0..7 (+32*kt)
    short8 ahi[4][4], alo[4][4];
    #pragma unroll
    for (int jt = 0; jt < 4; ++jt) {
        #pragma unroll
        for (int kt = 0; kt < 4; ++kt) {
            int j = (w << 6) + (jt << 4) + row;
            int g = jperm(j);
            const float* wr = W_hh + g * HID + (kt << 5) + (lk << 3);
            float4 wa = *reinterpret_cast<const float4*>(wr);
            float4 wb = *reinterpret_cast<const float4*>(wr + 4);
            float wf[8] = {wa.x, wa.y, wa.z, wa.w, wb.x, wb.y, wb.z, wb.w};
            short8 h8, l8;
            #pragma unroll
            for (int q = 0; q < 8; ++q) {
                short hq = f2bf(wf[q]);
                h8[q] = hq;
                l8[q] = f2bf(wf[q] - bf2f(hq));
            }
            ahi[jt][kt] = h8; alo[jt][kt] = l8;
        }
    }

    // per-lane pbias for its 16 (row, j) outputs: j = 64w + 16jt + 4lk + reg
    float4 pb[4];
    #pragma unroll
    for (int jt = 0; jt < 4; ++jt)
        pb[jt] = *reinterpret_cast<const float4*>(
            pbias + (b0 + row) * G4 + (w << 6) + (jt << 4) + (lk << 2));

    __syncthreads();

    // x for t=0
    float4 xc[4];
    {
        int v = rv_s[row][0];
        const float* xr = table + (long)v * G4 + (w << 6) + (lk << 2);
        #pragma unroll
        for (int jt = 0; jt < 4; ++jt) xc[jt] = *reinterpret_cast<const float4*>(xr + (jt << 4));
    }

    float cst[4] = {0.f, 0.f, 0.f, 0.f};   // c for this lane's 4 units (const-indexed only)
    int p = 0;
    const int rb = row << 8;
    const int sw = (row & 7) << 4;

    #pragma unroll 1
    for (int t = 0; t < TLEN; ++t) {
        // prefetch x(t+1): consumed next iteration -> full step of latency slack (L3-resident)
        float4 xn[4];
        {
            int v = rv_s[row][(t + 1) & (TLEN - 1)];
            const float* xr = table + (long)v * G4 + (w << 6) + (lk << 2);
            #pragma unroll
            for (int jt = 0; jt < 4; ++jt) xn[jt] = *reinterpret_cast<const float4*>(xr + (jt << 4));
        }

        const char* hhi_p = (const char*)hbuf[p][0];
        const char* hlo_p = (const char*)hbuf[p][1];

        f32x4 z4 = {0.f, 0.f, 0.f, 0.f};
        f32x4 acc[4] = {z4, z4, z4, z4};
        short8 bh[4];
        // B-frags (h_hi): lane reads h[row][kt*32 + lk*8 .. +7] (b128, swizzled -> ~2-way)
        #pragma unroll
        for (int kt = 0; kt < 4; ++kt) {
            int byte = (rb + (kt << 6) + (lk << 4)) ^ sw;
            bh[kt] = *reinterpret_cast<const short8*>(hhi_p + byte);
        }
        #pragma unroll
        for (int jt = 0; jt < 4; ++jt) {
            #pragma unroll
            for (int kt = 0; kt < 4; ++kt) {
                acc[jt] = __builtin_amdgcn_mfma_f32_16x16x32_bf16(ahi[jt][kt], bh[kt], acc[jt], 0, 0, 0);
                acc[jt] = __builtin_amdgcn_mfma_f32_16x16x32_bf16(alo[jt][kt], bh[kt], acc[jt], 0, 0, 0);
            }
        }
        // B-frags (h_lo), third split product
        #pragma unroll
        for (int kt = 0; kt < 4; ++kt) {
            int byte = (rb + (kt << 6) + (lk << 4)) ^ sw;
            bh[kt] = *reinterpret_cast<const short8*>(hlo_p + byte);
        }
        #pragma unroll
        for (int jt = 0; jt < 4; ++jt) {
            #pragma unroll
            for (int kt = 0; kt < 4; ++kt)
                acc[jt] = __builtin_amdgcn_mfma_f32_16x16x32_bf16(ahi[jt][kt], bh[kt], acc[jt], 0, 0, 0);
        }

        // epilogue: reg = gate (i,f,g,o), unit = 16w + 4jt + lk, batch row = l&15
        char* whi = (char*)hbuf[p ^ 1][0];
        char* wlo = (char*)hbuf[p ^ 1][1];
        #pragma unroll
        for (int jt = 0; jt < 4; ++jt) {
            float p0 = acc[jt][0] + xc[jt].x + pb[jt].x;
            float p1 = acc[jt][1] + xc[jt].y + pb[jt].y;
            float p2 = acc[jt][2] + xc[jt].z + pb[jt].z;
            float p3 = acc[jt][3] + xc[jt].w + pb[jt].w;
            float gi = sigm(p0), gf = sigm(p1), gg = tanh_fast(p2), go = sigm(p3);
            cst[jt] = gf * cst[jt] + gi * gg;
            float h = go * tanh_fast(cst[jt]);
            short hh = f2bf(h);
            short hl = f2bf(h - bf2f(hh));
            int unit = (w << 4) + (jt << 2) + lk;
            int byte = (rb + (unit << 1)) ^ sw;
            *reinterpret_cast<short*>(whi + byte) = hh;
            *reinterpret_cast<short*>(wlo + byte) = hl;
        }
        __syncthreads();
        p ^= 1;
        #pragma unroll
        for (int jt = 0; jt < 4; ++jt) xc[jt] = xn[jt];
    }

    // fused FC + sigmoid over final h (hbuf[p])
    {
        const char* fhi = (const char*)hbuf[p][0];
        const char* flo = (const char*)hbuf[p][1];
        int r = tid >> 5, seg = tid & 31;
        int byte = ((r << 8) + (seg << 3)) ^ ((r & 7) << 4);
        short4v h4 = *reinterpret_cast<const short4v*>(fhi + byte);
        short4v l4 = *reinterpret_cast<const short4v*>(flo + byte);
        float s = 0.f;
        #pragma unroll
        for (int q = 0; q < 4; ++q)
            s += (bf2f(h4[q]) + bf2f(l4[q])) * fc_w[(seg << 2) + q];
        #pragma unroll
        for (int off = 16; off >= 1; off >>= 1) s += __shfl_xor(s, off);
        if (seg == 0) out[b0 + r] = sigm(s + fc_b[0]);
    }
}

extern "C" void kernel_launch(void* const* d_in, const int* in_sizes, int n_in,
                              void* d_out, int out_size, void* d_ws, size_t ws_size,
                              hipStream_t stream) {
    const int*   review  = (const int*)d_in[0];
    const int*   product = (const int*)d_in[1];
    const float* emb     = (const float*)d_in[2];
    const float* pemb    = (const float*)d_in[3];
    const float* W_ih    = (const float*)d_in[4];
    const float* W_hh    = (const float*)d_in[5];
    const float* b_ih    = (const float*)d_in[6];
    const float* b_hh    = (const float*)d_in[7];
    const float* fc_w    = (const float*)d_in[8];
    const float* fc_b    = (const float*)d_in[9];
    float* out = (float*)d_out;

    char* ws = (char*)d_ws;
    float* Wt    = (float*)(ws);                       // 150*512*4   = 307200 B
    float* pbias = (float*)(ws + 307200);              // 256*512*4   = 524288 B
    float* table = (float*)(ws + 831488);              // 50000*512*4 = 102.4 MB

    k_transpose<<<(INDIM * G4 + 255) / 256, 256, 0, stream>>>(W_ih, Wt);
    k_pbias<<<BSZ, 256, 0, stream>>>(product, pemb, Wt, b_ih, b_hh, pbias);
    k_table<<<VOCAB / 16, 256, 0, stream>>>(emb, Wt, table);
    k_lstm<<<NBLK, 512, 0, stream>>>(review, W_hh, table, pbias, fc_w, fc_b, out);
}

// Round 13
// 909.594 us; speedup vs baseline: 1.1401x; 1.1401x over previous
//
#include <hip/hip_runtime.h>
#include <hip/hip_bf16.h>
#include <math.h>

#define VOCAB 50000
#define EMB 100
#define HID 128
#define NPROD 10000
#define PEMB 50
#define BSZ 256
#define TLEN 512
#define INDIM 150
#define G4 512        // 4*HID
#define RPB 16        // batch rows per k_lstm block
#define NBLK (BSZ/RPB)

typedef __attribute__((ext_vector_type(4))) float f32x4;
typedef __attribute__((ext_vector_type(8))) short short8;
typedef __attribute__((ext_vector_type(4))) short short4v;

__device__ __forceinline__ float sigm(float x) {
    return __builtin_amdgcn_rcpf(1.f + __expf(-x));
}
__device__ __forceinline__ short f2bf(float f) {
    __hip_bfloat16 h = __float2bfloat16(f);
    return __builtin_bit_cast(short, h);
}
__device__ __forceinline__ float bf2f(short s) {
    __hip_bfloat16 h = __builtin_bit_cast(__hip_bfloat16, s);
    return __bfloat162float(h);
}
// permuted column j (= 4*unit + gate) -> original gate row g (= gate*128 + unit)
__device__ __forceinline__ int jperm(int j) { return ((j & 3) << 7) + (j >> 2); }
__device__ __forceinline__ float clampf(float x, float lim) {
    return fminf(fmaxf(x, -lim), lim);
}

// ---------------- K0: Wt[d][j] = W_ih[g(j)][d]  (transpose + gate-interleave permute) ----------------
__global__ void k_transpose(const float* __restrict__ W_ih, float* __restrict__ Wt) {
    int idx = blockIdx.x * blockDim.x + threadIdx.x;
    if (idx < INDIM * G4) {
        int d = idx / G4, j = idx % G4;
        Wt[idx] = W_ih[jperm(j) * INDIM + d];
    }
}

// ---------------- K1: pbias[b][j] = b_ih[g(j)]+b_hh[g(j)] + pemb[product[b]] . W_ih[g(j),100:] ----------------
__global__ void k_pbias(const int* __restrict__ product,
                        const float* __restrict__ pemb,
                        const float* __restrict__ Wt,
                        const float* __restrict__ b_ih,
                        const float* __restrict__ b_hh,
                        float* __restrict__ pbias) {
    __shared__ float ep_s[PEMB];
    int b = blockIdx.x;
    int tid = threadIdx.x;
    int p = product[b];
    if (tid < PEMB) ep_s[tid] = pemb[p * PEMB + tid];
    __syncthreads();
    int j0 = tid, j1 = tid + 256;
    int g0 = jperm(j0), g1 = jperm(j1);
    float a0 = b_ih[g0] + b_hh[g0];
    float a1 = b_ih[g1] + b_hh[g1];
    #pragma unroll 5
    for (int d = 0; d < PEMB; ++d) {
        float e = ep_s[d];
        a0 += e * Wt[(EMB + d) * G4 + j0];
        a1 += e * Wt[(EMB + d) * G4 + j1];
    }
    pbias[b * G4 + j0] = a0;
    pbias[b * G4 + j1] = a1;
}

// ---------------- K2: table[v][j] = emb[v][:] . W_ih[g(j)][:100]  (permutation via Wt) ----------------
__global__ void k_table(const float* __restrict__ emb,
                        const float* __restrict__ Wt,
                        float* __restrict__ table) {
    __shared__ __align__(16) float es[16 * EMB];
    int v0 = blockIdx.x * 16;
    int tid = threadIdx.x;
    for (int l = tid; l < 16 * EMB; l += 256) es[l] = emb[v0 * EMB + l];
    __syncthreads();
    float acc0[16], acc1[16];
    #pragma unroll
    for (int r = 0; r < 16; ++r) { acc0[r] = 0.f; acc1[r] = 0.f; }
    #pragma unroll 5
    for (int k4 = 0; k4 < EMB / 4; ++k4) {
        float w0[4], w1[4];
        #pragma unroll
        for (int j = 0; j < 4; ++j) {
            w0[j] = Wt[(k4 * 4 + j) * G4 + tid];
            w1[j] = Wt[(k4 * 4 + j) * G4 + tid + 256];
        }
        #pragma unroll
        for (int r = 0; r < 16; ++r) {
            float4 e = *reinterpret_cast<const float4*>(&es[r * EMB + k4 * 4]);
            acc0[r] += e.x * w0[0] + e.y * w0[1] + e.z * w0[2] + e.w * w0[3];
            acc1[r] += e.x * w1[0] + e.y * w1[1] + e.z * w1[2] + e.w * w1[3];
        }
    }
    #pragma unroll
    for (int r = 0; r < 16; ++r) {
        table[(v0 + r) * G4 + tid]       = acc0[r];
        table[(v0 + r) * G4 + tid + 256] = acc1[r];
    }
}

// ---------------- K3: MFMA LSTM, 16 rows/block, 16 waves, 1 barrier/step ----------------
// Wave w owns j-cols [32w, 32w+32). Per lane: 2 units (jt=0,1), gates = acc regs.
// h stored bf16-only (no lo buffer); W keeps hi/lo split (A-operand, zero LDS cost).
// Epilogue: clamped combined-rcp nonlinearities (7 trans/unit vs 10).
__global__ void
__attribute__((amdgpu_flat_work_group_size(1024, 1024), amdgpu_waves_per_eu(4, 4)))
k_lstm(const int* __restrict__ review,
       const float* __restrict__ W_hh,
       const float* __restrict__ table,
       const float* __restrict__ pbias,
       const float* __restrict__ fc_w,
       const float* __restrict__ fc_b,
       float* __restrict__ out) {
    __shared__ int rv_s[RPB][TLEN + 1];
    __shared__ short hbuf[2][RPB * HID];   // [buf][swizzled row*128 + unit], bf16

    const int tid = threadIdx.x;
    const int w   = tid >> 6;        // wave 0..15
    const int l   = tid & 63;
    const int row = l & 15;          // batch row in tile / A j-row
    const int lk  = l >> 4;          // 0..3
    const int b0  = blockIdx.x * RPB;

    #pragma unroll 2
    for (int i = tid; i < RPB * TLEN; i += 1024)
        rv_s[i >> 9][i & 511] = review[(b0 + (i >> 9)) * TLEN + (i & 511)];
    if (tid < 512) {
        int4 z = {0, 0, 0, 0};
        ((int4*)hbuf)[tid] = z;
    }

    // A fragments: W rows for this lane, bf16 hi/lo split (W precision kept)
    short8 ahi[2][4], alo[2][4];
    #pragma unroll
    for (int jt = 0; jt < 2; ++jt) {
        #pragma unroll
        for (int kt = 0; kt < 4; ++kt) {
            int j = (w << 5) + (jt << 4) + row;
            int g = jperm(j);
            const float* wr = W_hh + g * HID + (kt << 5) + (lk << 3);
            float4 wa = *reinterpret_cast<const float4*>(wr);
            float4 wb = *reinterpret_cast<const float4*>(wr + 4);
            float wf[8] = {wa.x, wa.y, wa.z, wa.w, wb.x, wb.y, wb.z, wb.w};
            short8 h8, l8;
            #pragma unroll
            for (int q = 0; q < 8; ++q) {
                short hq = f2bf(wf[q]);
                h8[q] = hq;
                l8[q] = f2bf(wf[q] - bf2f(hq));
            }
            ahi[jt][kt] = h8; alo[jt][kt] = l8;
        }
    }

    float4 pb0 = *reinterpret_cast<const float4*>(pbias + (b0 + row) * G4 + (w << 5) + (lk << 2));
    float4 pb1 = *reinterpret_cast<const float4*>(pbias + (b0 + row) * G4 + (w << 5) + 16 + (lk << 2));

    __syncthreads();

    float4 xc0, xc1;
    {
        int v = rv_s[row][0];
        const float* xr = table + (long)v * G4 + (w << 5) + (lk << 2);
        xc0 = *reinterpret_cast<const float4*>(xr);
        xc1 = *reinterpret_cast<const float4*>(xr + 16);
    }

    float c0 = 0.f, c1 = 0.f;
    int p = 0;
    const int rb = row << 8;
    const int sw = (row & 7) << 4;
    const int u0 = (w << 3) + lk;        // unit for jt=0
    const int u1 = (w << 3) + 4 + lk;    // unit for jt=1

    #pragma unroll 1
    for (int t = 0; t < TLEN; ++t) {
        // prefetch x(t+1): consumed next iteration (full step of latency slack)
        float4 xn0, xn1;
        {
            int v = rv_s[row][(t + 1) & (TLEN - 1)];
            const float* xr = table + (long)v * G4 + (w << 5) + (lk << 2);
            xn0 = *reinterpret_cast<const float4*>(xr);
            xn1 = *reinterpret_cast<const float4*>(xr + 16);
        }

        const char* hp = (const char*)hbuf[p];
        short8 bh[4];
        #pragma unroll
        for (int kt = 0; kt < 4; ++kt)
            bh[kt] = *reinterpret_cast<const short8*>(hp + ((rb + (kt << 6) + (lk << 4)) ^ sw));

        f32x4 z4 = {0.f, 0.f, 0.f, 0.f};
        f32x4 acc0 = z4, acc1 = z4;
        #pragma unroll
        for (int kt = 0; kt < 4; ++kt) {
            acc0 = __builtin_amdgcn_mfma_f32_16x16x32_bf16(ahi[0][kt], bh[kt], acc0, 0, 0, 0);
            acc0 = __builtin_amdgcn_mfma_f32_16x16x32_bf16(alo[0][kt], bh[kt], acc0, 0, 0, 0);
        }
        #pragma unroll
        for (int kt = 0; kt < 4; ++kt) {
            acc1 = __builtin_amdgcn_mfma_f32_16x16x32_bf16(ahi[1][kt], bh[kt], acc1, 0, 0, 0);
            acc1 = __builtin_amdgcn_mfma_f32_16x16x32_bf16(alo[1][kt], bh[kt], acc1, 0, 0, 0);
        }

        // ---- epilogue: 2 units, combined-rcp nonlinearities ----
        float go0, go1;
        {
            float yi = clampf(acc0[0] + xc0.x + pb0.x, 15.f);
            float yf = clampf(acc0[1] + xc0.y + pb0.y, 15.f);
            float yg = clampf(acc0[2] + xc0.z + pb0.z, 9.f);
            float yo = clampf(acc0[3] + xc0.w + pb0.w, 15.f);
            float ei = __expf(-yi), ef = __expf(-yf), eg = __expf(-2.f * yg), eo = __expf(-yo);
            float di = 1.f + ei, df = 1.f + ef, dg = 1.f + eg, dq = 1.f + eo;
            float m01 = di * df, m012 = m01 * dg;
            float inv = __builtin_amdgcn_rcpf(m012 * dq);
            float inv012 = inv * dq;
            float gi = inv012 * (df * dg);
            float gf = inv012 * (di * dg);
            float gg = (1.f - eg) * (inv012 * m01);
            go0 = inv * m012;
            c0 = gf * c0 + gi * gg;
        }
        {
            float yi = clampf(acc1[0] + xc1.x + pb1.x, 15.f);
            float yf = clampf(acc1[1] + xc1.y + pb1.y, 15.f);
            float yg = clampf(acc1[2] + xc1.z + pb1.z, 9.f);
            float yo = clampf(acc1[3] + xc1.w + pb1.w, 15.f);
            float ei = __expf(-yi), ef = __expf(-yf), eg = __expf(-2.f * yg), eo = __expf(-yo);
            float di = 1.f + ei, df = 1.f + ef, dg = 1.f + eg, dq = 1.f + eo;
            float m01 = di * df, m012 = m01 * dg;
            float inv = __builtin_amdgcn_rcpf(m012 * dq);
            float inv012 = inv * dq;
            float gi = inv012 * (df * dg);
            float gf = inv012 * (di * dg);
            float gg = (1.f - eg) * (inv012 * m01);
            go1 = inv * m012;
            c1 = gf * c1 + gi * gg;
        }
        // phase 2: tanh(c0), tanh(c1) share one rcp
        {
            float z0 = clampf(c0, 9.f), z1 = clampf(c1, 9.f);
            float e0 = __expf(-2.f * z0), e1 = __expf(-2.f * z1);
            float d0 = 1.f + e0, d1 = 1.f + e1;
            float invc = __builtin_amdgcn_rcpf(d0 * d1);
            float h0 = go0 * ((1.f - e0) * (invc * d1));
            float h1 = go1 * ((1.f - e1) * (invc * d0));
            char* hw_ = (char*)hbuf[p ^ 1];
            *reinterpret_cast<short*>(hw_ + ((rb + (u0 << 1)) ^ sw)) = f2bf(h0);
            *reinterpret_cast<short*>(hw_ + ((rb + (u1 << 1)) ^ sw)) = f2bf(h1);
        }
        __syncthreads();
        p ^= 1;
        xc0 = xn0; xc1 = xn1;
    }

    // fused FC + sigmoid over final h (hbuf[p])
    if (tid < 512) {
        const char* fh = (const char*)hbuf[p];
        int r = tid >> 5, seg = tid & 31;
        int byte = ((r << 8) + (seg << 3)) ^ ((r & 7) << 4);
        short4v h4 = *reinterpret_cast<const short4v*>(fh + byte);
        float s = 0.f;
        #pragma unroll
        for (int q = 0; q < 4; ++q)
            s += bf2f(h4[q]) * fc_w[(seg << 2) + q];
        #pragma unroll
        for (int off = 16; off >= 1; off >>= 1) s += __shfl_xor(s, off);
        if (seg == 0) out[b0 + r] = sigm(s + fc_b[0]);
    }
}

extern "C" void kernel_launch(void* const* d_in, const int* in_sizes, int n_in,
                              void* d_out, int out_size, void* d_ws, size_t ws_size,
                              hipStream_t stream) {
    const int*   review  = (const int*)d_in[0];
    const int*   product = (const int*)d_in[1];
    const float* emb     = (const float*)d_in[2];
    const float* pemb    = (const float*)d_in[3];
    const float* W_ih    = (const float*)d_in[4];
    const float* W_hh    = (const float*)d_in[5];
    const float* b_ih    = (const float*)d_in[6];
    const float* b_hh    = (const float*)d_in[7];
    const float* fc_w    = (const float*)d_in[8];
    const float* fc_b    = (const float*)d_in[9];
    float* out = (float*)d_out;

    char* ws = (char*)d_ws;
    float* Wt    = (float*)(ws);                       // 150*512*4   = 307200 B
    float* pbias = (float*)(ws + 307200);              // 256*512*4   = 524288 B
    float* table = (float*)(ws + 831488);              // 50000*512*4 = 102.4 MB

    k_transpose<<<(INDIM * G4 + 255) / 256, 256, 0, stream>>>(W_ih, Wt);
    k_pbias<<<BSZ, 256, 0, stream>>>(product, pemb, Wt, b_ih, b_hh, pbias);
    k_table<<<VOCAB / 16, 256, 0, stream>>>(emb, Wt, table);
    k_lstm<<<NBLK, 1024, 0, stream>>>(review, W_hh, table, pbias, fc_w, fc_b, out);
}